// Round 11
// baseline (221.941 us; speedup 1.0000x reference)
//
#include <hip/hip_runtime.h>
#include <hip/hip_bf16.h>
#include <stdint.h>

#define INS 768
#define OUTS 64
#define BB 8
#define SS 2048
#define LDP 40

typedef __attribute__((ext_vector_type(8))) short short8;
typedef __attribute__((ext_vector_type(4))) float f32x4;

__device__ inline unsigned short f2bf(float f) {
  union { float f; uint32_t u; } v; v.f = f;
  uint32_t r = v.u + 0x7FFFu + ((v.u >> 16) & 1u);  // RNE
  return (unsigned short)(r >> 16);
}

// hardware packed f32->bf16 (v_cvt_pk_bf16_f32), RNE — same rounding as f2bf
__device__ inline short8 cvt8hw(float4 a, float4 b) {
  union { __hip_bfloat162 h[4]; short8 s; } u;
  u.h[0] = __float22bfloat162_rn(make_float2(a.x, a.y));
  u.h[1] = __float22bfloat162_rn(make_float2(a.z, a.w));
  u.h[2] = __float22bfloat162_rn(make_float2(b.x, b.y));
  u.h[3] = __float22bfloat162_rn(make_float2(b.z, b.w));
  return u.s;
}

// async global->LDS, 16B per lane, dest = wave-uniform base + lane*16
__device__ inline void gl_lds16(const void* g, void* l) {
  __builtin_amdgcn_global_load_lds(
      (const __attribute__((address_space(1))) uint32_t*)g,
      (__attribute__((address_space(3))) uint32_t*)l, 16, 0, 0);
}

__device__ inline void memfence_sched() { asm volatile("" ::: "memory"); }

#define PIPE_BARRIER(N)                                        \
  do {                                                         \
    asm volatile("s_waitcnt vmcnt(" #N ")" ::: "memory");      \
    __builtin_amdgcn_s_barrier();                              \
    __builtin_amdgcn_sched_barrier(0);                         \
  } while (0)

// ---------------- kernel 0: W -> W^T bf16 prep ------------------------------
// WT layout: [3][64][768] bf16, m=0 Q (pre-scaled by 0.125), m=1 K, m=2 V.
__global__ __launch_bounds__(256) void prep(
    const float* __restrict__ Wq, const float* __restrict__ Wk,
    const float* __restrict__ Wv, unsigned short* __restrict__ WT) {
  const int idx = blockIdx.x * 256 + threadIdx.x;   // 3*768*64 = 147456 total
  const int m = idx / (INS * OUTS);
  const int r = idx - m * (INS * OUTS);
  const int k = r >> 6, n = r & 63;
  const float* W = (m == 0) ? Wq : (m == 1) ? Wk : Wv;
  const float s = (m == 0) ? 0.125f : 1.0f;
  WT[((size_t)m * OUTS + n) * INS + k] = f2bf(W[(size_t)k * OUTS + n] * s);
}

// ---------------- kernel 1: QKV projection — R5 body, DIAGNOSTIC x3 ----------
// MEASUREMENT: body repeated 3x (idempotent; rep-local accumulators; epilogue
// rewrites identical values) so qkv surfaces in rocprof top-5 with counters.
// vmcnt seam: rep-n epilogue stores are OLDEST in the VMEM FIFO, so rep-n+1's
// kc=0 PIPE_BARRIER(4) retires them plus {stage0,wt0x3,stage1} — buf0/wb0
// ready exactly as in the single-shot R5 schedule.
__global__ __launch_bounds__(256) void qkv(
    const float* __restrict__ X, const unsigned short* __restrict__ WT,
    const float* __restrict__ bq, const float* __restrict__ bk,
    const float* __restrict__ bv,
    unsigned short* __restrict__ Qg, unsigned short* __restrict__ Kg,
    unsigned short* __restrict__ Vtg) {
  __shared__ __align__(16) float Xs[4][1024];   // 4 bufs x (32 rows x 32 f32)
  const int tid  = threadIdx.x;
  const int wave = tid >> 6, lane = tid & 63;
  const int quad = lane >> 4, l16 = lane & 15;
  const int chg  = wave;                        // 4 waves = 4 col-groups of 48
  const int row0 = blockIdx.x * 32;

  const int sr = tid >> 3, ss = tid & 7;
  const char* gsrc =
      (const char*)(X + (size_t)(row0 + sr) * INS) + ((ss ^ (sr & 7)) << 4);
  char* ldsb = (char*)&Xs[0][0] + wave * 1024;  // wave-uniform dest base

  const float* Bm[3]; float scl[3]; int col0[3];
  const unsigned short* Wt[3];
#pragma unroll
  for (int nt = 0; nt < 3; ++nt) {
    const int n0 = chg * 48 + nt * 16;
    const int mat = n0 >> 6;
    col0[nt] = n0 & 63;
    Wt[nt] = WT + ((size_t)mat * OUTS + col0[nt] + l16) * INS + quad * 8;
    if (mat == 0)      { Bm[nt] = bq; scl[nt] = 0.125f; }
    else if (mat == 1) { Bm[nt] = bk; scl[nt] = 1.0f; }
    else               { Bm[nt] = bv; scl[nt] = 1.0f; }
  }

  int off0[2], off1[2];
#pragma unroll
  for (int fr = 0; fr < 2; ++fr) {
    const int lr = fr * 16 + l16;
    off0[fr] = lr * 128 + ((((quad << 1)    ) ^ (lr & 7)) << 4);
    off1[fr] = lr * 128 + ((((quad << 1) | 1) ^ (lr & 7)) << 4);
  }

#pragma unroll 1
  for (int rep = 0; rep < 3; ++rep) {   // DIAGNOSTIC repeat — idempotent
    f32x4 acc[2][3];
#pragma unroll
    for (int fr = 0; fr < 2; ++fr)
#pragma unroll
      for (int nt = 0; nt < 3; ++nt) acc[fr][nt] = (f32x4){0.f, 0.f, 0.f, 0.f};

    short8 wb[3][3];   // ring: wt chunk (kc) lives in wb[kc%3]

    // prologue, order-pinned: s0; wt0 | s1; s2; wt1  (9 VMEM in flight)
    memfence_sched();
    gl_lds16(gsrc, ldsb);
#pragma unroll
    for (int nt = 0; nt < 3; ++nt)
      wb[0][nt] = *reinterpret_cast<const short8*>(Wt[nt]);
    memfence_sched();
    gl_lds16(gsrc + 128, ldsb + 4096);
    gl_lds16(gsrc + 256, ldsb + 8192);
#pragma unroll
    for (int nt = 0; nt < 3; ++nt)
      wb[1][nt] = *reinterpret_cast<const short8*>(Wt[nt] + 32);

#pragma unroll
    for (int kc = 0; kc < 24; ++kc) {
      if (kc <= 21)      PIPE_BARRIER(4);
      else if (kc == 22) PIPE_BARRIER(3);
      else               PIPE_BARRIER(0);

      const char* xb = (const char*)&Xs[0][0] + (kc & 3) * 4096;
      float4 f00 = *reinterpret_cast<const float4*>(xb + off0[0]);
      float4 f01 = *reinterpret_cast<const float4*>(xb + off1[0]);
      float4 f10 = *reinterpret_cast<const float4*>(xb + off0[1]);
      float4 f11 = *reinterpret_cast<const float4*>(xb + off1[1]);
      short8 a0 = cvt8hw(f00, f01);
      short8 a1 = cvt8hw(f10, f11);
#pragma unroll
      for (int nt = 0; nt < 3; ++nt) {
        acc[0][nt] = __builtin_amdgcn_mfma_f32_16x16x32_bf16(a0, wb[kc % 3][nt], acc[0][nt], 0, 0, 0);
        acc[1][nt] = __builtin_amdgcn_mfma_f32_16x16x32_bf16(a1, wb[kc % 3][nt], acc[1][nt], 0, 0, 0);
      }
      if (kc + 3 < 24)
        gl_lds16(gsrc + (size_t)(kc + 3) * 128, ldsb + (size_t)((kc + 3) & 3) * 4096);
      if (kc + 2 < 24) {
#pragma unroll
        for (int nt = 0; nt < 3; ++nt)
          wb[(kc + 2) % 3][nt] =
              *reinterpret_cast<const short8*>(Wt[nt] + (kc + 2) * 32);
      }
    }

    // epilogue (R6-proven mapping): Q,K row-major bf16; V transposed [bt][64][2048]
#pragma unroll
    for (int fr = 0; fr < 2; ++fr) {
      const int gm0 = row0 + fr * 16 + quad * 4;
#pragma unroll
      for (int nt = 0; nt < 3; ++nt) {
        const int n = chg * 48 + nt * 16 + l16;
        const float bias = Bm[nt][col0[nt] + l16] * scl[nt];
        if (n < 128) {
          unsigned short* dstbase = (n < 64) ? Qg : Kg;
          const int nn = n & 63;
#pragma unroll
          for (int r = 0; r < 4; ++r)
            dstbase[(size_t)(gm0 + r) * OUTS + nn] = f2bf(acc[fr][nt][r] + bias);
        } else {
          const int d = n - 128;
          const int batch = gm0 >> 11, s0 = gm0 & 2047;
          ushort4 pk;
          pk.x = f2bf(acc[fr][nt][0] + bias);
          pk.y = f2bf(acc[fr][nt][1] + bias);
          pk.z = f2bf(acc[fr][nt][2] + bias);
          pk.w = f2bf(acc[fr][nt][3] + bias);
          *reinterpret_cast<ushort4*>(&Vtg[((size_t)batch * OUTS + d) * SS + s0]) = pk;
        }
      }
    }
  }
}

// ---------------- kernel 2: attention — R5 tiles, 8-way kv split, hi-occ -----
// R10 counters: VGPR 180 capped residency at 2 waves/SIMD (8 waves/CU),
// OccupancyPercent 10.4%, all pipes idle -> latency-bound on TLP. Fix:
// KVBLK back to 32 (lean reg tiles), launch_bounds(256,4) forces VGPR<=128
// (4 waves/SIMD), 8-way kv split -> grid 1024, 3-buf ring LDS 34.8KB ->
// 4 blocks/CU co-resident = 16 waves/CU. Staging maps/swizzles R5-verbatim.
__global__ __launch_bounds__(256, 4) void attn(
    const unsigned short* __restrict__ Qg, const unsigned short* __restrict__ Kg,
    const unsigned short* __restrict__ Vtg,
    float* __restrict__ OP, float* __restrict__ LS) {
  __shared__ __align__(16) char KsB[3][4096];    // 32 rows x 128B, slot-swizzled
  __shared__ __align__(16) char VsB[3][4096];    // 64 rows x  64B, slot-swizzled
  __shared__ __align__(16) unsigned short Ps[4][2][16 * LDP];
  const int tid  = threadIdx.x;
  const int wave = tid >> 6, lane = tid & 63;
  const int quad = lane >> 4, l16 = lane & 15;
  const int bt  = blockIdx.x >> 7;               // 128 blocks per batch
  const int rem = blockIdx.x & 127;
  const int qb  = rem >> 3, ksl = rem & 7;       // 16 q-tiles x 8 kv-slices
  const int q0 = qb * 128 + wave * 32;
  const unsigned short* Qb = Qg + (size_t)bt * SS * OUTS;
  const unsigned short* Kb = Kg + (size_t)bt * SS * OUTS;
  const unsigned short* Vb = Vtg + (size_t)bt * OUTS * SS;
  const int jbeg = ksl * 256;

  // staging maps (R5-verbatim): wave stages 1KB of each tile per step
  const int krow = wave * 8 + (lane >> 3), ks8 = lane & 7;     // K: 128B rows
  const int vrow = wave * 16 + (lane >> 2), vs4 = lane & 3;    // V:  64B rows
  const int vsw  = (vrow & 3) ^ ((vrow >> 2) & 3);
  const char* ksrc = (const char*)(Kb + (size_t)(jbeg + krow) * OUTS) +
                     ((ks8 ^ (krow & 7)) << 4);
  const char* vsrc = (const char*)(Vb + (size_t)vrow * SS + jbeg) +
                     ((vs4 ^ vsw) << 4);

#define STAGE(kc)                                                            \
  do {                                                                       \
    gl_lds16(ksrc + (size_t)(kc) * 4096, &KsB[(kc) % 3][0] + wave * 1024);   \
    gl_lds16(vsrc + (size_t)(kc) * 64,   &VsB[(kc) % 3][0] + wave * 1024);   \
  } while (0)

  short8 aq[2][2];
#pragma unroll
  for (int mh = 0; mh < 2; ++mh)
#pragma unroll
    for (int ks = 0; ks < 2; ++ks)
      aq[mh][ks] = *reinterpret_cast<const short8*>(
          Qb + (size_t)(q0 + mh * 16 + l16) * OUTS + ks * 32 + quad * 8);

  // swizzled read offsets (R5-verbatim)
  int koff[2][2];   // [nt2][ks]
#pragma unroll
  for (int nt2 = 0; nt2 < 2; ++nt2)
#pragma unroll
    for (int ks = 0; ks < 2; ++ks)
      koff[nt2][ks] = (nt2 * 16 + l16) * 128 +
                      ((((ks << 2) | quad) ^ (l16 & 7)) << 4);
  int voff[4];      // [nt]
#pragma unroll
  for (int nt = 0; nt < 4; ++nt) {
    const int dr = nt * 16 + l16;
    voff[nt] = dr * 64 + ((quad ^ ((dr & 3) ^ ((dr >> 2) & 3))) << 4);
  }

  f32x4 oacc[2][4];
#pragma unroll
  for (int mh = 0; mh < 2; ++mh)
#pragma unroll
    for (int nt = 0; nt < 4; ++nt) oacc[mh][nt] = (f32x4){0.f, 0.f, 0.f, 0.f};
  float lsum[2][4] = {{0.f,0.f,0.f,0.f},{0.f,0.f,0.f,0.f}};

  // prologue: stage steps 0,1 (4 VMEM in flight)
  memfence_sched();
  STAGE(0);
  STAGE(1);

#pragma unroll
  for (int kc = 0; kc < 8; ++kc) {
    if (kc <= 6) PIPE_BARRIER(2);      // stage(kc) done; stage(kc+1) in flight
    else         PIPE_BARRIER(0);

    const char* kb8 = &KsB[kc % 3][0];
    const char* vb8 = &VsB[kc % 3][0];
    short8 bk[2][2], bv[4];
#pragma unroll
    for (int nt2 = 0; nt2 < 2; ++nt2)
#pragma unroll
      for (int ks = 0; ks < 2; ++ks)
        bk[nt2][ks] = *reinterpret_cast<const short8*>(kb8 + koff[nt2][ks]);
#pragma unroll
    for (int nt = 0; nt < 4; ++nt)
      bv[nt] = *reinterpret_cast<const short8*>(vb8 + voff[nt]);

#pragma unroll
    for (int mh = 0; mh < 2; ++mh) {
      f32x4 sc[2];
      sc[0] = (f32x4){0.f,0.f,0.f,0.f}; sc[1] = (f32x4){0.f,0.f,0.f,0.f};
#pragma unroll
      for (int ks = 0; ks < 2; ++ks)
#pragma unroll
        for (int nt2 = 0; nt2 < 2; ++nt2)
          sc[nt2] = __builtin_amdgcn_mfma_f32_16x16x32_bf16(aq[mh][ks], bk[nt2][ks], sc[nt2], 0, 0, 0);

      unsigned short* Pw = &Ps[wave][mh][0];
#pragma unroll
      for (int nt2 = 0; nt2 < 2; ++nt2)
#pragma unroll
        for (int r = 0; r < 4; ++r) {
          float p = __expf(sc[nt2][r]);
          lsum[mh][r] += p;
          Pw[(quad * 4 + r) * LDP + nt2 * 16 + l16] = f2bf(p);
        }
      short8 ap = *reinterpret_cast<const short8*>(&Pw[l16 * LDP + quad * 8]);
#pragma unroll
      for (int nt = 0; nt < 4; ++nt)
        oacc[mh][nt] = __builtin_amdgcn_mfma_f32_16x16x32_bf16(ap, bv[nt], oacc[mh][nt], 0, 0, 0);
    }

    if (kc + 2 < 8) STAGE(kc + 2);     // WAR on buf (kc-1)%3 safe past barrier
  }
#undef STAGE

#pragma unroll
  for (int st = 1; st < 16; st <<= 1)
#pragma unroll
    for (int mh = 0; mh < 2; ++mh)
#pragma unroll
      for (int r = 0; r < 4; ++r) lsum[mh][r] += __shfl_xor(lsum[mh][r], st, 64);

  float* OPb = OP + ((size_t)ksl * BB + bt) * SS * OUTS;
#pragma unroll
  for (int mh = 0; mh < 2; ++mh)
#pragma unroll
    for (int nt = 0; nt < 4; ++nt)
#pragma unroll
      for (int r = 0; r < 4; ++r) {
        int q = q0 + mh * 16 + quad * 4 + r;
        OPb[(size_t)q * OUTS + nt * 16 + l16] = oacc[mh][nt][r];
      }
  if (l16 == 0) {
#pragma unroll
    for (int mh = 0; mh < 2; ++mh)
#pragma unroll
      for (int r = 0; r < 4; ++r)
        LS[(size_t)ksl * BB * SS + bt * SS + q0 + mh * 16 + quad * 4 + r] = lsum[mh][r];
  }
}

// ---------------- kernel 3: combine key-split partials (8-way) ---------------
__global__ __launch_bounds__(256) void combine(
    const float* __restrict__ OP, const float* __restrict__ LS,
    float* __restrict__ out) {
  const size_t i4 = (size_t)blockIdx.x * 256 + threadIdx.x;  // float4 index
  const size_t row = (i4 * 4) >> 6;                          // bt*S + q
  float4 o = make_float4(0.f, 0.f, 0.f, 0.f);
  float l = 0.f;
#pragma unroll
  for (int ks = 0; ks < 8; ++ks) {
    float4 t = reinterpret_cast<const float4*>(OP + (size_t)ks * BB * SS * OUTS)[i4];
    o.x += t.x; o.y += t.y; o.z += t.z; o.w += t.w;
    l += LS[(size_t)ks * BB * SS + row];
  }
  const float inv = 1.0f / l;
  reinterpret_cast<float4*>(out)[i4] = make_float4(o.x * inv, o.y * inv, o.z * inv, o.w * inv);
}

extern "C" void kernel_launch(void* const* d_in, const int* in_sizes, int n_in,
                              void* d_out, int out_size, void* d_ws, size_t ws_size,
                              hipStream_t stream) {
  const float* X  = (const float*)d_in[0];
  const float* Wq = (const float*)d_in[1];
  const float* bq = (const float*)d_in[2];
  const float* Wk = (const float*)d_in[3];
  const float* bk = (const float*)d_in[4];
  const float* Wv = (const float*)d_in[5];
  const float* bv = (const float*)d_in[6];
  float* out = (float*)d_out;

  char* ws = (char*)d_ws;
  unsigned short* Qg  = (unsigned short*)(ws);                              // 2 MB
  unsigned short* Kg  = (unsigned short*)(ws + (size_t)2 * 1024 * 1024);    // 2 MB
  unsigned short* Vtg = (unsigned short*)(ws + (size_t)4 * 1024 * 1024);    // 2 MB
  unsigned short* WT  = (unsigned short*)(ws + (size_t)6 * 1024 * 1024);    // 295 KB
  float*          OP  = (float*)(ws + (size_t)7 * 1024 * 1024);             // 32 MB
  float*          LS  = (float*)(ws + (size_t)40 * 1024 * 1024);            // 512 KB

  prep<<<576, 256, 0, stream>>>(Wq, Wk, Wv, WT);
  qkv<<<512, 256, 0, stream>>>(X, WT, bq, bk, bv, Qg, Kg, Vtg);
  attn<<<1024, 256, 0, stream>>>(Qg, Kg, Vtg, OP, LS);
  combine<<<1024, 256, 0, stream>>>(OP, LS, out);
}

// Round 12
// 197.042 us; speedup vs baseline: 1.1264x; 1.1264x over previous
//
#include <hip/hip_runtime.h>
#include <hip/hip_bf16.h>
#include <stdint.h>

#define INS 768
#define OUTS 64
#define BB 8
#define SS 2048
#define LDP 40

typedef __attribute__((ext_vector_type(8))) short short8;
typedef __attribute__((ext_vector_type(4))) float f32x4;

__device__ inline unsigned short f2bf(float f) {
  union { float f; uint32_t u; } v; v.f = f;
  uint32_t r = v.u + 0x7FFFu + ((v.u >> 16) & 1u);  // RNE
  return (unsigned short)(r >> 16);
}

// hardware packed f32->bf16 (v_cvt_pk_bf16_f32), RNE — same rounding as f2bf
__device__ inline short8 cvt8hw(float4 a, float4 b) {
  union { __hip_bfloat162 h[4]; short8 s; } u;
  u.h[0] = __float22bfloat162_rn(make_float2(a.x, a.y));
  u.h[1] = __float22bfloat162_rn(make_float2(a.z, a.w));
  u.h[2] = __float22bfloat162_rn(make_float2(b.x, b.y));
  u.h[3] = __float22bfloat162_rn(make_float2(b.z, b.w));
  return u.s;
}

// async global->LDS, 16B per lane, dest = wave-uniform base + lane*16
__device__ inline void gl_lds16(const void* g, void* l) {
  __builtin_amdgcn_global_load_lds(
      (const __attribute__((address_space(1))) uint32_t*)g,
      (__attribute__((address_space(3))) uint32_t*)l, 16, 0, 0);
}

__device__ inline void memfence_sched() { asm volatile("" ::: "memory"); }

#define PIPE_BARRIER(N)                                        \
  do {                                                         \
    asm volatile("s_waitcnt vmcnt(" #N ")" ::: "memory");      \
    __builtin_amdgcn_s_barrier();                              \
    __builtin_amdgcn_sched_barrier(0);                         \
  } while (0)

// ---------------- kernel 0: W -> W^T bf16 prep ------------------------------
// WT layout: [3][64][768] bf16, m=0 Q (pre-scaled by 0.125), m=1 K, m=2 V.
__global__ __launch_bounds__(256) void prep(
    const float* __restrict__ Wq, const float* __restrict__ Wk,
    const float* __restrict__ Wv, unsigned short* __restrict__ WT) {
  const int idx = blockIdx.x * 256 + threadIdx.x;   // 3*768*64 = 147456 total
  const int m = idx / (INS * OUTS);
  const int r = idx - m * (INS * OUTS);
  const int k = r >> 6, n = r & 63;
  const float* W = (m == 0) ? Wq : (m == 1) ? Wk : Wv;
  const float s = (m == 0) ? 0.125f : 1.0f;
  WT[((size_t)m * OUTS + n) * INS + k] = f2bf(W[(size_t)k * OUTS + n] * s);
}

// ---------------- kernel 1: QKV — R5 pipeline, M=16/block, grid 1024 ---------
// R11 counters: qkv 25.1us/rep @ grid 512 (2 blk/CU, 8 waves/CU), MfmaUtil
// 7%, Occ 18.6% -> latency-bound on TLP. Fix: halve M to 16 rows -> grid
// 1024 -> 4 blk/CU = 16 waves/CU; launch_bounds(256,4) keeps VGPR<=128.
// Staging: lanes<32 of each wave stage 512B (wave w covers rows w*4..w*4+3);
// exec mask never 0 -> per-wave VMEM count stays 4/step (1 stage + 3 WT) ->
// R5's proven vmcnt(4) counted schedule unchanged. Per-output K-chain order
// identical to R5 -> bit-identical results.
__global__ __launch_bounds__(256, 4) void qkv(
    const float* __restrict__ X, const unsigned short* __restrict__ WT,
    const float* __restrict__ bq, const float* __restrict__ bk,
    const float* __restrict__ bv,
    unsigned short* __restrict__ Qg, unsigned short* __restrict__ Kg,
    unsigned short* __restrict__ Vtg) {
  __shared__ __align__(16) float Xs[4][512];    // 4 bufs x (16 rows x 32 f32)
  const int tid  = threadIdx.x;
  const int wave = tid >> 6, lane = tid & 63;
  const int quad = lane >> 4, l16 = lane & 15;
  const int chg  = wave;                        // 4 waves = 4 col-groups of 48
  const int row0 = blockIdx.x * 16;

  // staging map: lane<32; wave w rows w*4 + (lane>>3), slot lane&7
  const int sl = lane & 31;
  const int srow = wave * 4 + (sl >> 3), ss = sl & 7;
  const char* gsrc =
      (const char*)(X + (size_t)(row0 + srow) * INS) + ((ss ^ (srow & 7)) << 4);
  char* ldsb = (char*)&Xs[0][0] + wave * 512;   // wave-uniform dest base

  const float* Bm[3]; float scl[3]; int col0[3];
  const unsigned short* Wt[3];
#pragma unroll
  for (int nt = 0; nt < 3; ++nt) {
    const int n0 = chg * 48 + nt * 16;
    const int mat = n0 >> 6;
    col0[nt] = n0 & 63;
    Wt[nt] = WT + ((size_t)mat * OUTS + col0[nt] + l16) * INS + quad * 8;
    if (mat == 0)      { Bm[nt] = bq; scl[nt] = 0.125f; }
    else if (mat == 1) { Bm[nt] = bk; scl[nt] = 1.0f; }
    else               { Bm[nt] = bv; scl[nt] = 1.0f; }
  }

  // swizzled read offsets (rows 0..15, single m-frag)
  const int off0 = l16 * 128 + ((((quad << 1)    ) ^ (l16 & 7)) << 4);
  const int off1 = l16 * 128 + ((((quad << 1) | 1) ^ (l16 & 7)) << 4);

  f32x4 acc[3];
#pragma unroll
  for (int nt = 0; nt < 3; ++nt) acc[nt] = (f32x4){0.f, 0.f, 0.f, 0.f};

  short8 wb[3][3];   // ring: wt chunk (kc) lives in wb[kc%3]

  // prologue, order-pinned: s0; wt0 | s1; s2; wt1  (9 VMEM in flight/wave)
  if (lane < 32) gl_lds16(gsrc, ldsb);
#pragma unroll
  for (int nt = 0; nt < 3; ++nt)
    wb[0][nt] = *reinterpret_cast<const short8*>(Wt[nt]);
  memfence_sched();
  if (lane < 32) {
    gl_lds16(gsrc + 128, ldsb + 2048);
    gl_lds16(gsrc + 256, ldsb + 4096);
  }
#pragma unroll
  for (int nt = 0; nt < 3; ++nt)
    wb[1][nt] = *reinterpret_cast<const short8*>(Wt[nt] + 32);

#pragma unroll
  for (int kc = 0; kc < 24; ++kc) {
    if (kc <= 21)      PIPE_BARRIER(4);
    else if (kc == 22) PIPE_BARRIER(3);
    else               PIPE_BARRIER(0);

    const char* xb = (const char*)&Xs[0][0] + (kc & 3) * 2048;
    float4 f00 = *reinterpret_cast<const float4*>(xb + off0);
    float4 f01 = *reinterpret_cast<const float4*>(xb + off1);
    short8 a0 = cvt8hw(f00, f01);
#pragma unroll
    for (int nt = 0; nt < 3; ++nt)
      acc[nt] = __builtin_amdgcn_mfma_f32_16x16x32_bf16(a0, wb[kc % 3][nt], acc[nt], 0, 0, 0);

    if (kc + 3 < 24) {
      if (lane < 32)
        gl_lds16(gsrc + (size_t)(kc + 3) * 128,
                 ldsb + (size_t)((kc + 3) & 3) * 2048);
      else
        memfence_sched();
    }
    if (kc + 2 < 24) {
#pragma unroll
      for (int nt = 0; nt < 3; ++nt)
        wb[(kc + 2) % 3][nt] =
            *reinterpret_cast<const short8*>(Wt[nt] + (kc + 2) * 32);
    }
  }

  // epilogue (R6-proven mapping): Q,K row-major bf16; V transposed [bt][64][2048]
  {
    const int gm0 = row0 + quad * 4;
#pragma unroll
    for (int nt = 0; nt < 3; ++nt) {
      const int n = chg * 48 + nt * 16 + l16;
      const float bias = Bm[nt][col0[nt] + l16] * scl[nt];
      if (n < 128) {
        unsigned short* dstbase = (n < 64) ? Qg : Kg;
        const int nn = n & 63;
#pragma unroll
        for (int r = 0; r < 4; ++r)
          dstbase[(size_t)(gm0 + r) * OUTS + nn] = f2bf(acc[nt][r] + bias);
      } else {
        const int d = n - 128;
        const int batch = gm0 >> 11, s0 = gm0 & 2047;
        ushort4 pk;
        pk.x = f2bf(acc[nt][0] + bias);
        pk.y = f2bf(acc[nt][1] + bias);
        pk.z = f2bf(acc[nt][2] + bias);
        pk.w = f2bf(acc[nt][3] + bias);
        *reinterpret_cast<ushort4*>(&Vtg[((size_t)batch * OUTS + d) * SS + s0]) = pk;
      }
    }
  }
}

// ---------------- kernel 2: attention — lean regs, 4-way split, 4 blk/CU -----
// R11 post-mortem: lean tiles + launch_bounds(256,4) fixed occupancy (VGPR
// 64) but the 8-way split doubled OP+K/V traffic and regressed. This is the
// same lean kernel on the R5-proven 4-way split: grid 512, OP 16MB, 16
// steps, 3-buf counted ring (LDS 34.8KB -> 4 blk/CU = 16 waves/CU vs the
// VGPR-180-capped 8 of the measured 25.4us baseline).
__global__ __launch_bounds__(256, 4) void attn(
    const unsigned short* __restrict__ Qg, const unsigned short* __restrict__ Kg,
    const unsigned short* __restrict__ Vtg,
    float* __restrict__ OP, float* __restrict__ LS) {
  __shared__ __align__(16) char KsB[3][4096];    // 32 rows x 128B, slot-swizzled
  __shared__ __align__(16) char VsB[3][4096];    // 64 rows x  64B, slot-swizzled
  __shared__ __align__(16) unsigned short Ps[4][2][16 * LDP];
  const int tid  = threadIdx.x;
  const int wave = tid >> 6, lane = tid & 63;
  const int quad = lane >> 4, l16 = lane & 15;
  const int bt  = blockIdx.x >> 6;
  const int rem = blockIdx.x & 63;
  const int qb  = rem >> 2, ksl = rem & 3;
  const int q0 = qb * 128 + wave * 32;
  const unsigned short* Qb = Qg + (size_t)bt * SS * OUTS;
  const unsigned short* Kb = Kg + (size_t)bt * SS * OUTS;
  const unsigned short* Vb = Vtg + (size_t)bt * OUTS * SS;
  const int jbeg = ksl * 512;

  // staging maps (R5-verbatim): wave stages 1KB of each tile per step
  const int krow = wave * 8 + (lane >> 3), ks8 = lane & 7;     // K: 128B rows
  const int vrow = wave * 16 + (lane >> 2), vs4 = lane & 3;    // V:  64B rows
  const int vsw  = (vrow & 3) ^ ((vrow >> 2) & 3);
  const char* ksrc = (const char*)(Kb + (size_t)(jbeg + krow) * OUTS) +
                     ((ks8 ^ (krow & 7)) << 4);
  const char* vsrc = (const char*)(Vb + (size_t)vrow * SS + jbeg) +
                     ((vs4 ^ vsw) << 4);

#define STAGE(kc)                                                            \
  do {                                                                       \
    gl_lds16(ksrc + (size_t)(kc) * 4096, &KsB[(kc) % 3][0] + wave * 1024);   \
    gl_lds16(vsrc + (size_t)(kc) * 64,   &VsB[(kc) % 3][0] + wave * 1024);   \
  } while (0)

  short8 aq[2][2];
#pragma unroll
  for (int mh = 0; mh < 2; ++mh)
#pragma unroll
    for (int ks = 0; ks < 2; ++ks)
      aq[mh][ks] = *reinterpret_cast<const short8*>(
          Qb + (size_t)(q0 + mh * 16 + l16) * OUTS + ks * 32 + quad * 8);

  // swizzled read offsets (R5-verbatim)
  int koff[2][2];   // [nt2][ks]
#pragma unroll
  for (int nt2 = 0; nt2 < 2; ++nt2)
#pragma unroll
    for (int ks = 0; ks < 2; ++ks)
      koff[nt2][ks] = (nt2 * 16 + l16) * 128 +
                      ((((ks << 2) | quad) ^ (l16 & 7)) << 4);
  int voff[4];      // [nt]
#pragma unroll
  for (int nt = 0; nt < 4; ++nt) {
    const int dr = nt * 16 + l16;
    voff[nt] = dr * 64 + ((quad ^ ((dr & 3) ^ ((dr >> 2) & 3))) << 4);
  }

  f32x4 oacc[2][4];
#pragma unroll
  for (int mh = 0; mh < 2; ++mh)
#pragma unroll
    for (int nt = 0; nt < 4; ++nt) oacc[mh][nt] = (f32x4){0.f, 0.f, 0.f, 0.f};
  float lsum[2][4] = {{0.f,0.f,0.f,0.f},{0.f,0.f,0.f,0.f}};

  // prologue: stage steps 0,1 (4 VMEM in flight)
  memfence_sched();
  STAGE(0);
  STAGE(1);

#pragma unroll
  for (int kc = 0; kc < 16; ++kc) {
    if (kc <= 14) PIPE_BARRIER(2);     // stage(kc) done; stage(kc+1) in flight
    else          PIPE_BARRIER(0);

    const char* kb8 = &KsB[kc % 3][0];
    const char* vb8 = &VsB[kc % 3][0];
    short8 bk[2][2], bv[4];
#pragma unroll
    for (int nt2 = 0; nt2 < 2; ++nt2)
#pragma unroll
      for (int ks = 0; ks < 2; ++ks)
        bk[nt2][ks] = *reinterpret_cast<const short8*>(kb8 + koff[nt2][ks]);
#pragma unroll
    for (int nt = 0; nt < 4; ++nt)
      bv[nt] = *reinterpret_cast<const short8*>(vb8 + voff[nt]);

#pragma unroll
    for (int mh = 0; mh < 2; ++mh) {
      f32x4 sc[2];
      sc[0] = (f32x4){0.f,0.f,0.f,0.f}; sc[1] = (f32x4){0.f,0.f,0.f,0.f};
#pragma unroll
      for (int ks = 0; ks < 2; ++ks)
#pragma unroll
        for (int nt2 = 0; nt2 < 2; ++nt2)
          sc[nt2] = __builtin_amdgcn_mfma_f32_16x16x32_bf16(aq[mh][ks], bk[nt2][ks], sc[nt2], 0, 0, 0);

      unsigned short* Pw = &Ps[wave][mh][0];
#pragma unroll
      for (int nt2 = 0; nt2 < 2; ++nt2)
#pragma unroll
        for (int r = 0; r < 4; ++r) {
          float p = __expf(sc[nt2][r]);
          lsum[mh][r] += p;
          Pw[(quad * 4 + r) * LDP + nt2 * 16 + l16] = f2bf(p);
        }
      short8 ap = *reinterpret_cast<const short8*>(&Pw[l16 * LDP + quad * 8]);
#pragma unroll
      for (int nt = 0; nt < 4; ++nt)
        oacc[mh][nt] = __builtin_amdgcn_mfma_f32_16x16x32_bf16(ap, bv[nt], oacc[mh][nt], 0, 0, 0);
    }

    if (kc + 2 < 16) STAGE(kc + 2);    // WAR on buf (kc-1)%3 safe past barrier
  }
#undef STAGE

#pragma unroll
  for (int st = 1; st < 16; st <<= 1)
#pragma unroll
    for (int mh = 0; mh < 2; ++mh)
#pragma unroll
      for (int r = 0; r < 4; ++r) lsum[mh][r] += __shfl_xor(lsum[mh][r], st, 64);

  float* OPb = OP + ((size_t)ksl * BB + bt) * SS * OUTS;
#pragma unroll
  for (int mh = 0; mh < 2; ++mh)
#pragma unroll
    for (int nt = 0; nt < 4; ++nt)
#pragma unroll
      for (int r = 0; r < 4; ++r) {
        int q = q0 + mh * 16 + quad * 4 + r;
        OPb[(size_t)q * OUTS + nt * 16 + l16] = oacc[mh][nt][r];
      }
  if (l16 == 0) {
#pragma unroll
    for (int mh = 0; mh < 2; ++mh)
#pragma unroll
      for (int r = 0; r < 4; ++r)
        LS[(size_t)ksl * BB * SS + bt * SS + q0 + mh * 16 + quad * 4 + r] = lsum[mh][r];
  }
}

// ---------------- kernel 3: combine key-split partials (R5 VERBATIM) ---------
__global__ __launch_bounds__(256) void combine(
    const float* __restrict__ OP, const float* __restrict__ LS,
    float* __restrict__ out) {
  const size_t i4 = (size_t)blockIdx.x * 256 + threadIdx.x;  // float4 index
  const size_t row = (i4 * 4) >> 6;                          // bt*S + q
  float4 o = make_float4(0.f, 0.f, 0.f, 0.f);
  float l = 0.f;
#pragma unroll
  for (int ks = 0; ks < 4; ++ks) {
    float4 t = reinterpret_cast<const float4*>(OP + (size_t)ks * BB * SS * OUTS)[i4];
    o.x += t.x; o.y += t.y; o.z += t.z; o.w += t.w;
    l += LS[(size_t)ks * BB * SS + row];
  }
  const float inv = 1.0f / l;
  reinterpret_cast<float4*>(out)[i4] = make_float4(o.x * inv, o.y * inv, o.z * inv, o.w * inv);
}

extern "C" void kernel_launch(void* const* d_in, const int* in_sizes, int n_in,
                              void* d_out, int out_size, void* d_ws, size_t ws_size,
                              hipStream_t stream) {
  const float* X  = (const float*)d_in[0];
  const float* Wq = (const float*)d_in[1];
  const float* bq = (const float*)d_in[2];
  const float* Wk = (const float*)d_in[3];
  const float* bk = (const float*)d_in[4];
  const float* Wv = (const float*)d_in[5];
  const float* bv = (const float*)d_in[6];
  float* out = (float*)d_out;

  char* ws = (char*)d_ws;
  unsigned short* Qg  = (unsigned short*)(ws);                              // 2 MB
  unsigned short* Kg  = (unsigned short*)(ws + (size_t)2 * 1024 * 1024);    // 2 MB
  unsigned short* Vtg = (unsigned short*)(ws + (size_t)4 * 1024 * 1024);    // 2 MB
  unsigned short* WT  = (unsigned short*)(ws + (size_t)6 * 1024 * 1024);    // 295 KB
  float*          OP  = (float*)(ws + (size_t)7 * 1024 * 1024);             // 16 MB
  float*          LS  = (float*)(ws + (size_t)23 * 1024 * 1024);            // 256 KB

  prep<<<576, 256, 0, stream>>>(Wq, Wk, Wv, WT);
  qkv<<<1024, 256, 0, stream>>>(X, WT, bq, bk, bv, Qg, Kg, Vtg);
  attn<<<512, 256, 0, stream>>>(Qg, Kg, Vtg, OP, LS);
  combine<<<1024, 256, 0, stream>>>(OP, LS, out);
}

// Round 13
// 137.932 us; speedup vs baseline: 1.6091x; 1.4285x over previous
//
#include <hip/hip_runtime.h>
#include <hip/hip_bf16.h>
#include <stdint.h>

#define INS 768
#define OUTS 64
#define BB 8
#define SS 2048
#define LDP 40

typedef __attribute__((ext_vector_type(8))) short short8;
typedef __attribute__((ext_vector_type(4))) float f32x4;

__device__ inline unsigned short f2bf(float f) {
  union { float f; uint32_t u; } v; v.f = f;
  uint32_t r = v.u + 0x7FFFu + ((v.u >> 16) & 1u);  // RNE
  return (unsigned short)(r >> 16);
}

// hardware packed f32->bf16 (v_cvt_pk_bf16_f32), RNE — same rounding as f2bf
__device__ inline short8 cvt8hw(float4 a, float4 b) {
  union { __hip_bfloat162 h[4]; short8 s; } u;
  u.h[0] = __float22bfloat162_rn(make_float2(a.x, a.y));
  u.h[1] = __float22bfloat162_rn(make_float2(a.z, a.w));
  u.h[2] = __float22bfloat162_rn(make_float2(b.x, b.y));
  u.h[3] = __float22bfloat162_rn(make_float2(b.z, b.w));
  return u.s;
}

// async global->LDS, 16B per lane, dest = wave-uniform base + lane*16
__device__ inline void gl_lds16(const void* g, void* l) {
  __builtin_amdgcn_global_load_lds(
      (const __attribute__((address_space(1))) uint32_t*)g,
      (__attribute__((address_space(3))) uint32_t*)l, 16, 0, 0);
}

__device__ inline void memfence_sched() { asm volatile("" ::: "memory"); }

#define PIPE_BARRIER(N)                                        \
  do {                                                         \
    asm volatile("s_waitcnt vmcnt(" #N ")" ::: "memory");      \
    __builtin_amdgcn_s_barrier();                              \
    __builtin_amdgcn_sched_barrier(0);                         \
  } while (0)

// ---------------- kernel 0: W -> W^T bf16 prep ------------------------------
// WT layout: [3][64][768] bf16, m=0 Q (pre-scaled by 0.125), m=1 K, m=2 V.
__global__ __launch_bounds__(256) void prep(
    const float* __restrict__ Wq, const float* __restrict__ Wk,
    const float* __restrict__ Wv, unsigned short* __restrict__ WT) {
  const int idx = blockIdx.x * 256 + threadIdx.x;   // 3*768*64 = 147456 total
  const int m = idx / (INS * OUTS);
  const int r = idx - m * (INS * OUTS);
  const int k = r >> 6, n = r & 63;
  const float* W = (m == 0) ? Wq : (m == 1) ? Wk : Wv;
  const float s = (m == 0) ? 0.125f : 1.0f;
  WT[((size_t)m * OUTS + n) * INS + k] = f2bf(W[(size_t)k * OUTS + n] * s);
}

// ---------------- kernel 1: QKV projection (R5 VERBATIM — proven 25us) -------
// R12 post-mortem: M=16 doubled WT L2 traffic (WT bytes are per-WAVE
// invariant) -> regressed to ~42us. Restored M=32 / grid 512 exactly.
__global__ __launch_bounds__(256) void qkv(
    const float* __restrict__ X, const unsigned short* __restrict__ WT,
    const float* __restrict__ bq, const float* __restrict__ bk,
    const float* __restrict__ bv,
    unsigned short* __restrict__ Qg, unsigned short* __restrict__ Kg,
    unsigned short* __restrict__ Vtg) {
  __shared__ __align__(16) float Xs[4][1024];   // 4 bufs x (32 rows x 32 f32)
  const int tid  = threadIdx.x;
  const int wave = tid >> 6, lane = tid & 63;
  const int quad = lane >> 4, l16 = lane & 15;
  const int chg  = wave;                        // 4 waves = 4 col-groups of 48
  const int row0 = blockIdx.x * 32;

  const int sr = tid >> 3, ss = tid & 7;
  const char* gsrc =
      (const char*)(X + (size_t)(row0 + sr) * INS) + ((ss ^ (sr & 7)) << 4);
  char* ldsb = (char*)&Xs[0][0] + wave * 1024;  // wave-uniform dest base

  const float* Bm[3]; float scl[3]; int col0[3];
  const unsigned short* Wt[3];
#pragma unroll
  for (int nt = 0; nt < 3; ++nt) {
    const int n0 = chg * 48 + nt * 16;
    const int mat = n0 >> 6;
    col0[nt] = n0 & 63;
    Wt[nt] = WT + ((size_t)mat * OUTS + col0[nt] + l16) * INS + quad * 8;
    if (mat == 0)      { Bm[nt] = bq; scl[nt] = 0.125f; }
    else if (mat == 1) { Bm[nt] = bk; scl[nt] = 1.0f; }
    else               { Bm[nt] = bv; scl[nt] = 1.0f; }
  }

  int off0[2], off1[2];
#pragma unroll
  for (int fr = 0; fr < 2; ++fr) {
    const int lr = fr * 16 + l16;
    off0[fr] = lr * 128 + ((((quad << 1)    ) ^ (lr & 7)) << 4);
    off1[fr] = lr * 128 + ((((quad << 1) | 1) ^ (lr & 7)) << 4);
  }

  f32x4 acc[2][3];
#pragma unroll
  for (int fr = 0; fr < 2; ++fr)
#pragma unroll
    for (int nt = 0; nt < 3; ++nt) acc[fr][nt] = (f32x4){0.f, 0.f, 0.f, 0.f};

  short8 wb[3][3];   // ring: wt chunk (kc) lives in wb[kc%3]

  // prologue, order-pinned: s0; wt0 | s1; s2; wt1  (9 VMEM in flight)
  gl_lds16(gsrc, ldsb);
#pragma unroll
  for (int nt = 0; nt < 3; ++nt)
    wb[0][nt] = *reinterpret_cast<const short8*>(Wt[nt]);
  memfence_sched();
  gl_lds16(gsrc + 128, ldsb + 4096);
  gl_lds16(gsrc + 256, ldsb + 8192);
#pragma unroll
  for (int nt = 0; nt < 3; ++nt)
    wb[1][nt] = *reinterpret_cast<const short8*>(Wt[nt] + 32);

#pragma unroll
  for (int kc = 0; kc < 24; ++kc) {
    if (kc <= 21)      PIPE_BARRIER(4);
    else if (kc == 22) PIPE_BARRIER(3);
    else               PIPE_BARRIER(0);

    const char* xb = (const char*)&Xs[0][0] + (kc & 3) * 4096;
    float4 f00 = *reinterpret_cast<const float4*>(xb + off0[0]);
    float4 f01 = *reinterpret_cast<const float4*>(xb + off1[0]);
    float4 f10 = *reinterpret_cast<const float4*>(xb + off0[1]);
    float4 f11 = *reinterpret_cast<const float4*>(xb + off1[1]);
    short8 a0 = cvt8hw(f00, f01);
    short8 a1 = cvt8hw(f10, f11);
#pragma unroll
    for (int nt = 0; nt < 3; ++nt) {
      acc[0][nt] = __builtin_amdgcn_mfma_f32_16x16x32_bf16(a0, wb[kc % 3][nt], acc[0][nt], 0, 0, 0);
      acc[1][nt] = __builtin_amdgcn_mfma_f32_16x16x32_bf16(a1, wb[kc % 3][nt], acc[1][nt], 0, 0, 0);
    }
    if (kc + 3 < 24)
      gl_lds16(gsrc + (size_t)(kc + 3) * 128, ldsb + (size_t)((kc + 3) & 3) * 4096);
    if (kc + 2 < 24) {
#pragma unroll
      for (int nt = 0; nt < 3; ++nt)
        wb[(kc + 2) % 3][nt] =
            *reinterpret_cast<const short8*>(Wt[nt] + (kc + 2) * 32);
    }
  }

  // epilogue (R6-proven mapping): Q,K row-major bf16; V transposed [bt][64][2048]
#pragma unroll
  for (int fr = 0; fr < 2; ++fr) {
    const int gm0 = row0 + fr * 16 + quad * 4;
#pragma unroll
    for (int nt = 0; nt < 3; ++nt) {
      const int n = chg * 48 + nt * 16 + l16;
      const float bias = Bm[nt][col0[nt] + l16] * scl[nt];
      if (n < 128) {
        unsigned short* dstbase = (n < 64) ? Qg : Kg;
        const int nn = n & 63;
#pragma unroll
        for (int r = 0; r < 4; ++r)
          dstbase[(size_t)(gm0 + r) * OUTS + nn] = f2bf(acc[fr][nt][r] + bias);
      } else {
        const int d = n - 128;
        const int batch = gm0 >> 11, s0 = gm0 & 2047;
        ushort4 pk;
        pk.x = f2bf(acc[fr][nt][0] + bias);
        pk.y = f2bf(acc[fr][nt][1] + bias);
        pk.z = f2bf(acc[fr][nt][2] + bias);
        pk.w = f2bf(acc[fr][nt][3] + bias);
        *reinterpret_cast<ushort4*>(&Vtg[((size_t)batch * OUTS + d) * SS + s0]) = pk;
      }
    }
  }
}

// ---------------- kernel 2: attention — lean regs, 3-buf ring, NO vgpr bound -
// R12 post-mortem: launch_bounds(256,4) forced VGPR 64 on a ~110-reg kernel
// -> ~150MB/dispatch scratch spill traffic (WRITE 117MB), 65us. Same kernel
// with the bound REMOVED: natural VGPR ~110-125 <= 128 -> 4 waves/SIMD
// allowed; LDS 34.8KB -> 4 blocks/CU -> 16 waves/CU at R5-identical traffic.
// Math / kv order R5-identical (refchecked R11/R12).
__global__ __launch_bounds__(256) void attn(
    const unsigned short* __restrict__ Qg, const unsigned short* __restrict__ Kg,
    const unsigned short* __restrict__ Vtg,
    float* __restrict__ OP, float* __restrict__ LS) {
  __shared__ __align__(16) char KsB[3][4096];    // 32 rows x 128B, slot-swizzled
  __shared__ __align__(16) char VsB[3][4096];    // 64 rows x  64B, slot-swizzled
  __shared__ __align__(16) unsigned short Ps[4][2][16 * LDP];
  const int tid  = threadIdx.x;
  const int wave = tid >> 6, lane = tid & 63;
  const int quad = lane >> 4, l16 = lane & 15;
  const int bt  = blockIdx.x >> 6;
  const int rem = blockIdx.x & 63;
  const int qb  = rem >> 2, ksl = rem & 3;
  const int q0 = qb * 128 + wave * 32;
  const unsigned short* Qb = Qg + (size_t)bt * SS * OUTS;
  const unsigned short* Kb = Kg + (size_t)bt * SS * OUTS;
  const unsigned short* Vb = Vtg + (size_t)bt * OUTS * SS;
  const int jbeg = ksl * 512;

  // staging maps (R5-verbatim): wave stages 1KB of each tile per step
  const int krow = wave * 8 + (lane >> 3), ks8 = lane & 7;     // K: 128B rows
  const int vrow = wave * 16 + (lane >> 2), vs4 = lane & 3;    // V:  64B rows
  const int vsw  = (vrow & 3) ^ ((vrow >> 2) & 3);
  const char* ksrc = (const char*)(Kb + (size_t)(jbeg + krow) * OUTS) +
                     ((ks8 ^ (krow & 7)) << 4);
  const char* vsrc = (const char*)(Vb + (size_t)vrow * SS + jbeg) +
                     ((vs4 ^ vsw) << 4);

#define STAGE(kc)                                                            \
  do {                                                                       \
    gl_lds16(ksrc + (size_t)(kc) * 4096, &KsB[(kc) % 3][0] + wave * 1024);   \
    gl_lds16(vsrc + (size_t)(kc) * 64,   &VsB[(kc) % 3][0] + wave * 1024);   \
  } while (0)

  short8 aq[2][2];
#pragma unroll
  for (int mh = 0; mh < 2; ++mh)
#pragma unroll
    for (int ks = 0; ks < 2; ++ks)
      aq[mh][ks] = *reinterpret_cast<const short8*>(
          Qb + (size_t)(q0 + mh * 16 + l16) * OUTS + ks * 32 + quad * 8);

  // swizzled read offsets (R5-verbatim)
  int koff[2][2];   // [nt2][ks]
#pragma unroll
  for (int nt2 = 0; nt2 < 2; ++nt2)
#pragma unroll
    for (int ks = 0; ks < 2; ++ks)
      koff[nt2][ks] = (nt2 * 16 + l16) * 128 +
                      ((((ks << 2) | quad) ^ (l16 & 7)) << 4);
  int voff[4];      // [nt]
#pragma unroll
  for (int nt = 0; nt < 4; ++nt) {
    const int dr = nt * 16 + l16;
    voff[nt] = dr * 64 + ((quad ^ ((dr & 3) ^ ((dr >> 2) & 3))) << 4);
  }

  f32x4 oacc[2][4];
#pragma unroll
  for (int mh = 0; mh < 2; ++mh)
#pragma unroll
    for (int nt = 0; nt < 4; ++nt) oacc[mh][nt] = (f32x4){0.f, 0.f, 0.f, 0.f};
  float lsum[2][4] = {{0.f,0.f,0.f,0.f},{0.f,0.f,0.f,0.f}};

  // prologue: stage steps 0,1 (4 VMEM in flight)
  memfence_sched();
  STAGE(0);
  STAGE(1);

#pragma unroll
  for (int kc = 0; kc < 16; ++kc) {
    if (kc <= 14) PIPE_BARRIER(2);     // stage(kc) done; stage(kc+1) in flight
    else          PIPE_BARRIER(0);

    const char* kb8 = &KsB[kc % 3][0];
    const char* vb8 = &VsB[kc % 3][0];
    short8 bk[2][2], bv[4];
#pragma unroll
    for (int nt2 = 0; nt2 < 2; ++nt2)
#pragma unroll
      for (int ks = 0; ks < 2; ++ks)
        bk[nt2][ks] = *reinterpret_cast<const short8*>(kb8 + koff[nt2][ks]);
#pragma unroll
    for (int nt = 0; nt < 4; ++nt)
      bv[nt] = *reinterpret_cast<const short8*>(vb8 + voff[nt]);

#pragma unroll
    for (int mh = 0; mh < 2; ++mh) {
      f32x4 sc[2];
      sc[0] = (f32x4){0.f,0.f,0.f,0.f}; sc[1] = (f32x4){0.f,0.f,0.f,0.f};
#pragma unroll
      for (int ks = 0; ks < 2; ++ks)
#pragma unroll
        for (int nt2 = 0; nt2 < 2; ++nt2)
          sc[nt2] = __builtin_amdgcn_mfma_f32_16x16x32_bf16(aq[mh][ks], bk[nt2][ks], sc[nt2], 0, 0, 0);

      unsigned short* Pw = &Ps[wave][mh][0];
#pragma unroll
      for (int nt2 = 0; nt2 < 2; ++nt2)
#pragma unroll
        for (int r = 0; r < 4; ++r) {
          float p = __expf(sc[nt2][r]);
          lsum[mh][r] += p;
          Pw[(quad * 4 + r) * LDP + nt2 * 16 + l16] = f2bf(p);
        }
      short8 ap = *reinterpret_cast<const short8*>(&Pw[l16 * LDP + quad * 8]);
#pragma unroll
      for (int nt = 0; nt < 4; ++nt)
        oacc[mh][nt] = __builtin_amdgcn_mfma_f32_16x16x32_bf16(ap, bv[nt], oacc[mh][nt], 0, 0, 0);
    }

    if (kc + 2 < 16) STAGE(kc + 2);    // WAR on buf (kc-1)%3 safe past barrier
  }
#undef STAGE

#pragma unroll
  for (int st = 1; st < 16; st <<= 1)
#pragma unroll
    for (int mh = 0; mh < 2; ++mh)
#pragma unroll
      for (int r = 0; r < 4; ++r) lsum[mh][r] += __shfl_xor(lsum[mh][r], st, 64);

  float* OPb = OP + ((size_t)ksl * BB + bt) * SS * OUTS;
#pragma unroll
  for (int mh = 0; mh < 2; ++mh)
#pragma unroll
    for (int nt = 0; nt < 4; ++nt)
#pragma unroll
      for (int r = 0; r < 4; ++r) {
        int q = q0 + mh * 16 + quad * 4 + r;
        OPb[(size_t)q * OUTS + nt * 16 + l16] = oacc[mh][nt][r];
      }
  if (l16 == 0) {
#pragma unroll
    for (int mh = 0; mh < 2; ++mh)
#pragma unroll
      for (int r = 0; r < 4; ++r)
        LS[(size_t)ksl * BB * SS + bt * SS + q0 + mh * 16 + quad * 4 + r] = lsum[mh][r];
  }
}

// ---------------- kernel 3: combine key-split partials (R5 VERBATIM) ---------
__global__ __launch_bounds__(256) void combine(
    const float* __restrict__ OP, const float* __restrict__ LS,
    float* __restrict__ out) {
  const size_t i4 = (size_t)blockIdx.x * 256 + threadIdx.x;  // float4 index
  const size_t row = (i4 * 4) >> 6;                          // bt*S + q
  float4 o = make_float4(0.f, 0.f, 0.f, 0.f);
  float l = 0.f;
#pragma unroll
  for (int ks = 0; ks < 4; ++ks) {
    float4 t = reinterpret_cast<const float4*>(OP + (size_t)ks * BB * SS * OUTS)[i4];
    o.x += t.x; o.y += t.y; o.z += t.z; o.w += t.w;
    l += LS[(size_t)ks * BB * SS + row];
  }
  const float inv = 1.0f / l;
  reinterpret_cast<float4*>(out)[i4] = make_float4(o.x * inv, o.y * inv, o.z * inv, o.w * inv);
}

extern "C" void kernel_launch(void* const* d_in, const int* in_sizes, int n_in,
                              void* d_out, int out_size, void* d_ws, size_t ws_size,
                              hipStream_t stream) {
  const float* X  = (const float*)d_in[0];
  const float* Wq = (const float*)d_in[1];
  const float* bq = (const float*)d_in[2];
  const float* Wk = (const float*)d_in[3];
  const float* bk = (const float*)d_in[4];
  const float* Wv = (const float*)d_in[5];
  const float* bv = (const float*)d_in[6];
  float* out = (float*)d_out;

  char* ws = (char*)d_ws;
  unsigned short* Qg  = (unsigned short*)(ws);                              // 2 MB
  unsigned short* Kg  = (unsigned short*)(ws + (size_t)2 * 1024 * 1024);    // 2 MB
  unsigned short* Vtg = (unsigned short*)(ws + (size_t)4 * 1024 * 1024);    // 2 MB
  unsigned short* WT  = (unsigned short*)(ws + (size_t)6 * 1024 * 1024);    // 295 KB
  float*          OP  = (float*)(ws + (size_t)7 * 1024 * 1024);             // 16 MB
  float*          LS  = (float*)(ws + (size_t)23 * 1024 * 1024);            // 256 KB

  prep<<<576, 256, 0, stream>>>(Wq, Wk, Wv, WT);
  qkv<<<512, 256, 0, stream>>>(X, WT, bq, bk, bv, Qg, Kg, Vtg);
  attn<<<512, 256, 0, stream>>>(Qg, Kg, Vtg, OP, LS);
  combine<<<1024, 256, 0, stream>>>(OP, LS, out);
}